// Round 2
// baseline (319.644 us; speedup 1.0000x reference)
//
#include <hip/hip_runtime.h>
#include <hip/hip_bf16.h>

// Problem: out[n] = sigmoid( u[n] . W[type_idx[n]] . v[n] ),  N=131072, D=256, K=8
// Strategy: group-by-type -> grouped skinny GEMM (fp16 MFMA), v kept fp32 exact.
// (Round 1 was a GPU-acquisition infra failure; identical resubmission.)

#define N_SAMPLES 131072
#define DIM 256
#define KTYPES 8
#define TILE_M 64                      // rows per workgroup (4 waves x 16)
#define MAXTILES (N_SAMPLES / TILE_M + KTYPES)   // 2048 + 8 = 2056

typedef _Float16 f16x8 __attribute__((ext_vector_type(8)));
typedef float f32x4 __attribute__((ext_vector_type(4)));

// ---------------- ws layout ----------------
// [0, 1MB)          : Wt fp16  [k][e][d]
// +0x100000         : counts[8]  (zeroed)
// +0x100020         : cursors[8] (zeroed)
// +0x100040         : goff[8]
// +0x100080         : desc[MAXTILES] int4
// +0x100080+2056*16 : perm[N] int
#define WT_OFF   ((size_t)0)
#define CNT_OFF  ((size_t)0x100000)
#define CUR_OFF  ((size_t)0x100020)
#define GOF_OFF  ((size_t)0x100040)
#define DESC_OFF ((size_t)0x100080)
#define PERM_OFF (DESC_OFF + (size_t)MAXTILES * 16)

// Pass A: W fp32 [k][d][e] -> Wt fp16 [k][e][d]  (transposed for B-fragment reads)
__global__ void convw_kernel(const float* __restrict__ W, _Float16* __restrict__ Wt) {
    int g = blockIdx.x * 256 + threadIdx.x;    // 131072 threads
    int d  = g & 255;
    int e0 = ((g >> 8) & 63) * 4;
    int k  = g >> 14;
    const float* src = W + ((size_t)k << 16) + (size_t)d * 256 + e0;
    float4 vv = *(const float4*)src;
    _Float16* dst = Wt + ((size_t)k << 16) + d;
    dst[(size_t)(e0 + 0) * 256] = (_Float16)vv.x;
    dst[(size_t)(e0 + 1) * 256] = (_Float16)vv.y;
    dst[(size_t)(e0 + 2) * 256] = (_Float16)vv.z;
    dst[(size_t)(e0 + 3) * 256] = (_Float16)vv.w;
}

// Pass B: histogram of type_idx
__global__ void hist_kernel(const int* __restrict__ idx, int* __restrict__ counts) {
    __shared__ int lcnt[KTYPES];
    if (threadIdx.x < KTYPES) lcnt[threadIdx.x] = 0;
    __syncthreads();
    int n = blockIdx.x * 256 + threadIdx.x;
    atomicAdd(&lcnt[idx[n]], 1);
    __syncthreads();
    if (threadIdx.x < KTYPES && lcnt[threadIdx.x] > 0)
        atomicAdd(&counts[threadIdx.x], lcnt[threadIdx.x]);
}

// Pass C: prefix offsets + tile descriptors (single block)
__global__ void plan_kernel(const int* __restrict__ counts, int* __restrict__ goff,
                            int4* __restrict__ desc) {
    __shared__ int s_goff[KTYPES + 1], s_tstart[KTYPES + 1], s_cnt[KTYPES];
    if (threadIdx.x == 0) {
        int off = 0, toff = 0;
        for (int k = 0; k < KTYPES; ++k) {
            int c = counts[k];
            s_cnt[k] = c;
            s_goff[k] = off; s_tstart[k] = toff;
            goff[k] = off;
            off += c;
            toff += (c + TILE_M - 1) / TILE_M;
        }
        s_goff[KTYPES] = off; s_tstart[KTYPES] = toff;
    }
    __syncthreads();
    int total = s_tstart[KTYPES];
    for (int t = threadIdx.x; t < MAXTILES; t += blockDim.x) {
        int4 dd;
        if (t < total) {
            int k = 0;
            while (t >= s_tstart[k + 1]) ++k;
            dd.x = k;
            dd.y = (t - s_tstart[k]) * TILE_M;
            dd.z = s_goff[k];
            dd.w = s_cnt[k];
        } else {
            dd = make_int4(-1, 0, 0, 0);
        }
        desc[t] = dd;
    }
}

// Pass D: scatter sample ids into per-type contiguous regions of perm
__global__ void scatter_kernel(const int* __restrict__ idx, const int* __restrict__ goff,
                               int* __restrict__ cursors, int* __restrict__ perm) {
    __shared__ int lcnt[KTYPES], lbase[KTYPES];
    int tid = threadIdx.x;
    if (tid < KTYPES) lcnt[tid] = 0;
    __syncthreads();
    int n = blockIdx.x * 256 + tid;
    int k = idx[n];
    int lpos = atomicAdd(&lcnt[k], 1);
    __syncthreads();
    if (tid < KTYPES)
        lbase[tid] = (lcnt[tid] > 0) ? atomicAdd(&cursors[tid], lcnt[tid]) : 0;
    __syncthreads();
    perm[goff[k] + lbase[k] + lpos] = n;
}

// Pass E: grouped GEMM tile.  4 waves x 16 rows. e-chunks of 32 staged in LDS.
// MFMA fragment maps (gfx950 16x16x32):
//   A[m][kk]: m = lane&15, kk = (lane>>4)*8 + j
//   B[kk][n]: n = lane&15, kk = (lane>>4)*8 + j
//   D[m][n] : n = lane&15, m = (lane>>4)*4 + r
__global__ __launch_bounds__(256, 4) void bilinear_main(
    const float* __restrict__ U, const float* __restrict__ V,
    const _Float16* __restrict__ Wt, const int* __restrict__ perm,
    const int4* __restrict__ desc, float* __restrict__ out)
{
    int4 dsc = desc[blockIdx.x];
    int k = dsc.x;
    if (k < 0) return;
    int local_base = dsc.y, goff = dsc.z, count = dsc.w;

    __shared__ __align__(16) _Float16 Wlds[32 * 256];  // 16 KB, XOR-swizzled

    int tid  = threadIdx.x;
    int wave = tid >> 6, lane = tid & 63;
    int lq = lane >> 4, lm = lane & 15;

    const _Float16* Wk = Wt + ((size_t)k << 16);

    // ---- A fragments: row = wave*16 + lm, kept in registers across all e-chunks
    int arow_local = wave * 16 + lm;
    bool avalid = (local_base + arow_local) < count;
    int an = perm[goff + local_base + (avalid ? arow_local : 0)];
    f16x8 afrag[8];
    {
        const float* up = U + ((size_t)an << 8) + lq * 8;
        #pragma unroll
        for (int ks = 0; ks < 8; ++ks) {
            float4 f0 = *(const float4*)(up + ks * 32);
            float4 f1 = *(const float4*)(up + ks * 32 + 4);
            f16x8 a;
            a[0] = (_Float16)f0.x; a[1] = (_Float16)f0.y;
            a[2] = (_Float16)f0.z; a[3] = (_Float16)f0.w;
            a[4] = (_Float16)f1.x; a[5] = (_Float16)f1.y;
            a[6] = (_Float16)f1.z; a[7] = (_Float16)f1.w;
            afrag[ks] = a;
        }
    }

    // ---- rows this lane accumulates in C/D: row = wave*16 + lq*4 + r
    int vrow[4]; bool vvalid[4];
    #pragma unroll
    for (int r = 0; r < 4; ++r) {
        int rl = wave * 16 + lq * 4 + r;
        vvalid[r] = (local_base + rl) < count;
        vrow[r] = perm[goff + local_base + (vvalid[r] ? rl : 0)];
    }

    float spart[4] = {0.f, 0.f, 0.f, 0.f};

    for (int ec = 0; ec < 8; ++ec) {
        __syncthreads();
        // stage W[d][e] slice e in [ec*32, ec*32+32) as Wlds[e_local][d], swizzled
        #pragma unroll
        for (int it = 0; it < 4; ++it) {
            int elem = (it * 256 + tid) * 8;          // 0..8191
            int e_l = elem >> 8, d0 = elem & 255;
            int byte = (e_l * 512 + d0 * 2) ^ ((e_l & 7) << 4);
            *(f16x8*)((char*)Wlds + byte) =
                *(const f16x8*)(Wk + (size_t)((ec * 32 + e_l) << 8) + d0);
        }
        __syncthreads();

        f32x4 acc0 = {0.f, 0.f, 0.f, 0.f};
        f32x4 acc1 = {0.f, 0.f, 0.f, 0.f};
        #pragma unroll
        for (int ks = 0; ks < 8; ++ks) {
            int dd = ks * 32 + lq * 8;
            int b0off = (lm * 512 + dd * 2) ^ ((lm & 7) << 4);
            int b1off = ((16 + lm) * 512 + dd * 2) ^ ((lm & 7) << 4);
            f16x8 b0 = *(const f16x8*)((char*)Wlds + b0off);
            f16x8 b1 = *(const f16x8*)((char*)Wlds + b1off);
            acc0 = __builtin_amdgcn_mfma_f32_16x16x32_f16(afrag[ks], b0, acc0, 0, 0, 0);
            acc1 = __builtin_amdgcn_mfma_f32_16x16x32_f16(afrag[ks], b1, acc1, 0, 0, 0);
        }
        // multiply T chunk by fp32 v and accumulate
        #pragma unroll
        for (int r = 0; r < 4; ++r) {
            const float* vp = V + ((size_t)vrow[r] << 8) + ec * 32;
            spart[r] += acc0[r] * vp[lm] + acc1[r] * vp[16 + lm];
        }
    }

    // reduce over the 16 e-lanes (lm), lq preserved by masks 1,2,4,8
    #pragma unroll
    for (int r = 0; r < 4; ++r) {
        float s = spart[r];
        s += __shfl_xor(s, 1);
        s += __shfl_xor(s, 2);
        s += __shfl_xor(s, 4);
        s += __shfl_xor(s, 8);
        spart[r] = s;
    }
    if (lm < 4 && vvalid[lm]) {
        float s = spart[lm];
        out[vrow[lm]] = 1.0f / (1.0f + __expf(-s));
    }
}

extern "C" void kernel_launch(void* const* d_in, const int* in_sizes, int n_in,
                              void* d_out, int out_size, void* d_ws, size_t ws_size,
                              hipStream_t stream) {
    const float* U = (const float*)d_in[0];
    const float* V = (const float*)d_in[1];
    const float* W = (const float*)d_in[2];
    const int* idx = (const int*)d_in[3];
    float* out = (float*)d_out;
    char* ws = (char*)d_ws;

    _Float16* Wt  = (_Float16*)(ws + WT_OFF);
    int* counts   = (int*)(ws + CNT_OFF);
    int* cursors  = (int*)(ws + CUR_OFF);
    int* goff     = (int*)(ws + GOF_OFF);
    int4* desc    = (int4*)(ws + DESC_OFF);
    int* perm     = (int*)(ws + PERM_OFF);

    hipMemsetAsync(ws + CNT_OFF, 0, 64, stream);                  // counts + cursors
    convw_kernel<<<512, 256, 0, stream>>>(W, Wt);
    hist_kernel<<<512, 256, 0, stream>>>(idx, counts);
    plan_kernel<<<1, 256, 0, stream>>>(counts, goff, desc);
    scatter_kernel<<<512, 256, 0, stream>>>(idx, goff, cursors, perm);
    bilinear_main<<<MAXTILES, 256, 0, stream>>>(U, V, Wt, perm, desc, out);
}